// Round 1
// baseline (224.389 us; speedup 1.0000x reference)
//
#include <hip/hip_runtime.h>
#include <math.h>

// ---------- types ----------
typedef __bf16 bf16_t;
typedef __bf16 bf16x8 __attribute__((ext_vector_type(8)));
typedef __bf16 bf16x4 __attribute__((ext_vector_type(4)));
typedef float  f32x4  __attribute__((ext_vector_type(4)));

#define MFMA16(a, b, c) __builtin_amdgcn_mfma_f32_16x16x32_bf16((a), (b), (c), 0, 0, 0)

// Problem constants
// B=2, N=M=2048, QUERY_DIM=CONTEXT_DIM=1024, HEADS=8, DIM_HEAD=64, INNER=512
#define BN_ROWS 4096    // B*N = B*M
#define QDIM    1024
#define INNER   512
#define NHEAD   8
#define DHEAD   64

// ---------- fp32 -> bf16 convert (x4 vectorized) ----------
__global__ __launch_bounds__(256) void cvt_k(const float* __restrict__ in,
                                             bf16_t* __restrict__ out, int n4) {
  int i = blockIdx.x * 256 + threadIdx.x;
  if (i < n4) {
    float4 f = ((const float4*)in)[i];
    bf16x4 v = { (bf16_t)f.x, (bf16_t)f.y, (bf16_t)f.z, (bf16_t)f.w };
    ((bf16x4*)out)[i] = v;
  }
}

// ---------- weight transpose+convert: W[K][N] f32 -> WT[N][K] bf16 ----------
__global__ __launch_bounds__(256) void wtrans_k(const float* __restrict__ Wq,
                                                const float* __restrict__ Wk,
                                                const float* __restrict__ Wv,
                                                const float* __restrict__ Wo,
                                                bf16_t* __restrict__ WqT,
                                                bf16_t* __restrict__ WkT,
                                                bf16_t* __restrict__ WvT,
                                                bf16_t* __restrict__ WoT) {
  int z = blockIdx.y;
  const float* W; bf16_t* WT; int K, N;
  if (z == 0)      { W = Wq; WT = WqT; K = 1024; N = 512; }
  else if (z == 1) { W = Wk; WT = WkT; K = 1024; N = 512; }
  else if (z == 2) { W = Wv; WT = WvT; K = 1024; N = 512; }
  else             { W = Wo; WT = WoT; K = 512;  N = 1024; }
  int tK = K >> 6;
  int bid = blockIdx.x;            // 128 tiles either way
  int kt = bid % tK, nt = bid / tK;
  int k0 = kt << 6, n0 = nt << 6;
  __shared__ float tile[64][65];
  for (int idx = threadIdx.x; idx < 4096; idx += 256) {
    int r = idx >> 6, c = idx & 63;
    tile[r][c] = W[(size_t)(k0 + r) * N + n0 + c];
  }
  __syncthreads();
  for (int idx = threadIdx.x; idx < 4096; idx += 256) {
    int r = idx >> 6, c = idx & 63;   // r: n-local, c: k-local
    WT[(size_t)(n0 + r) * K + k0 + c] = (bf16_t)tile[c][r];
  }
}

// ---------- V transpose: Vb[4096][512] bf16 -> Vt[bh=16][d=64][key=2048] ----------
__global__ __launch_bounds__(256) void vtrans_k(const bf16_t* __restrict__ Vb,
                                                bf16_t* __restrict__ Vt) {
  int m0 = blockIdx.x << 6;          // key tile
  int bh = blockIdx.y;               // 0..15
  int b = bh >> 3, h = bh & 7;
  __shared__ bf16_t tile[64][65];
  for (int idx = threadIdx.x; idx < 4096; idx += 256) {
    int r = idx >> 6, c = idx & 63;  // r: key-local, c: d
    tile[r][c] = Vb[(size_t)(b * 2048 + m0 + r) * INNER + h * DHEAD + c];
  }
  __syncthreads();
  for (int idx = threadIdx.x; idx < 4096; idx += 256) {
    int r = idx >> 6, c = idx & 63;  // r: d, c: key-local
    Vt[((size_t)bh * 64 + r) * 2048 + m0 + c] = tile[c][r];
  }
}

// ---------- 128x128 GEMM core: C = A[M][K] @ Bt[N][K]^T ----------
// LDS row stride 40 bf16 (=80B, 16B-aligned, breaks the stride-32 8-way conflict)
__device__ __forceinline__ void gemm128(const bf16_t* __restrict__ A,
                                        const bf16_t* __restrict__ Bt,
                                        int K, int N, int row0, int n0, float scale,
                                        bf16_t* __restrict__ Cb, float* __restrict__ Cf,
                                        const float* __restrict__ bias) {
  __shared__ bf16_t As[128 * 40];
  __shared__ bf16_t Bs[128 * 40];
  const int tid = threadIdx.x;
  const int w = tid >> 6, lane = tid & 63, quad = lane >> 4, l16 = lane & 15;
  const int sr = tid >> 2, sc = (tid & 3) << 3;   // staging: row, col(8-elem chunk)
  const bf16_t* ga = A  + (size_t)(row0 + sr) * K + sc;
  const bf16_t* gb = Bt + (size_t)(n0  + sr) * K + sc;

  f32x4 acc[4][4];
#pragma unroll
  for (int i = 0; i < 4; ++i)
#pragma unroll
    for (int j = 0; j < 4; ++j) acc[i][j] = f32x4{0.f, 0.f, 0.f, 0.f};

  int4 ra0 = *(const int4*)(ga);
  int4 ra1 = *(const int4*)(ga + (size_t)64 * K);
  int4 rb0 = *(const int4*)(gb);
  int4 rb1 = *(const int4*)(gb + (size_t)64 * K);

  const int mrow = (w & 1) << 6, ncol = (w >> 1) << 6;
  const int KT = K >> 5;
  for (int kt = 0; kt < KT; ++kt) {
    __syncthreads();
    *(int4*)&As[sr * 40 + sc]        = ra0;
    *(int4*)&As[(sr + 64) * 40 + sc] = ra1;
    *(int4*)&Bs[sr * 40 + sc]        = rb0;
    *(int4*)&Bs[(sr + 64) * 40 + sc] = rb1;
    __syncthreads();
    if (kt + 1 < KT) {
      int k0 = (kt + 1) << 5;
      ra0 = *(const int4*)(ga + k0);
      ra1 = *(const int4*)(ga + (size_t)64 * K + k0);
      rb0 = *(const int4*)(gb + k0);
      rb1 = *(const int4*)(gb + (size_t)64 * K + k0);
    }
    bf16x8 af[4], bfr[4];
#pragma unroll
    for (int i = 0; i < 4; ++i)
      af[i] = *(const bf16x8*)&As[(mrow + i * 16 + l16) * 40 + quad * 8];
#pragma unroll
    for (int j = 0; j < 4; ++j)
      bfr[j] = *(const bf16x8*)&Bs[(ncol + j * 16 + l16) * 40 + quad * 8];
#pragma unroll
    for (int i = 0; i < 4; ++i)
#pragma unroll
      for (int j = 0; j < 4; ++j)
        acc[i][j] = MFMA16(af[i], bfr[j], acc[i][j]);
  }
  // epilogue: C/D layout col=lane&15, row=quad*4+reg (m89/m91 verified)
#pragma unroll
  for (int i = 0; i < 4; ++i) {
    int row = row0 + mrow + i * 16 + quad * 4;
#pragma unroll
    for (int j = 0; j < 4; ++j) {
      int col = n0 + ncol + j * 16 + l16;
#pragma unroll
      for (int r = 0; r < 4; ++r) {
        if (Cf) Cf[(size_t)(row + r) * N + col] = acc[i][j][r] + bias[col];
        else    Cb[(size_t)(row + r) * N + col] = (bf16_t)(acc[i][j][r] * scale);
      }
    }
  }
}

__global__ __launch_bounds__(256, 2) void gemm_qkv_k(const bf16_t* __restrict__ xb,
                                                     const bf16_t* __restrict__ cb,
                                                     const bf16_t* __restrict__ WqT,
                                                     const bf16_t* __restrict__ WkT,
                                                     const bf16_t* __restrict__ WvT,
                                                     bf16_t* __restrict__ Qb,
                                                     bf16_t* __restrict__ Kb,
                                                     bf16_t* __restrict__ Vb) {
  int z = blockIdx.z;
  const bf16_t* A  = (z == 0) ? xb : cb;
  const bf16_t* Bt = (z == 0) ? WqT : (z == 1) ? WkT : WvT;
  bf16_t* C        = (z == 0) ? Qb  : (z == 1) ? Kb  : Vb;
  float scale      = (z == 0) ? 0.125f : 1.0f;   // SCALE=1/8 folded into Q, exact
  gemm128(A, Bt, 1024, 512, blockIdx.y * 128, blockIdx.x * 128, scale, C, nullptr, nullptr);
}

__global__ __launch_bounds__(256, 2) void gemm_out_k(const bf16_t* __restrict__ AO,
                                                     const bf16_t* __restrict__ WoT,
                                                     const float* __restrict__ bo,
                                                     float* __restrict__ out) {
  gemm128(AO, WoT, 512, 1024, blockIdx.y * 128, blockIdx.x * 128, 1.0f, nullptr, out, bo);
}

// ---------- flash attention ----------
// Grid: (32 q-tiles of 64 rows, 16 bh). Block 256 = 4 waves, 16 q-rows/wave.
// Q pre-scaled by 1/8. LDS row stride 72 (=144B, 16B aligned, 2-way banks = free).
__global__ __launch_bounds__(256, 4) void attn_k(const bf16_t* __restrict__ Qb,
                                                 const bf16_t* __restrict__ Kb,
                                                 const bf16_t* __restrict__ Vt,
                                                 bf16_t* __restrict__ AO) {
  const int tid = threadIdx.x;
  const int w = tid >> 6, lane = tid & 63, quad = lane >> 4, l16 = lane & 15;
  const int qt = blockIdx.x;        // 0..31
  const int bh = blockIdx.y;        // 0..15
  const int b = bh >> 3, h = bh & 7;

  __shared__ bf16_t Ks[64 * 72];
  __shared__ bf16_t Vs[64 * 72];
  __shared__ bf16_t Ps[64 * 72];

  // Q a-frags direct from global: A[m=lane&15][k=quad*8+j]
  const bf16_t* qptr = Qb + ((size_t)(b * 2048 + qt * 64 + w * 16 + l16)) * INNER + h * DHEAD;
  bf16x8 aq[2];
  aq[0] = *(const bf16x8*)(qptr + quad * 8);
  aq[1] = *(const bf16x8*)(qptr + 32 + quad * 8);

  f32x4 o[4];
#pragma unroll
  for (int dt = 0; dt < 4; ++dt) o[dt] = f32x4{0.f, 0.f, 0.f, 0.f};
  float m_r[4], l_r[4];
#pragma unroll
  for (int r = 0; r < 4; ++r) { m_r[r] = -__builtin_inff(); l_r[r] = 0.f; }

  const bf16_t* kbase  = Kb + ((size_t)b * 2048) * INNER + h * DHEAD;
  const bf16_t* vtbase = Vt + ((size_t)bh * 64) * 2048;

  const int sr = tid >> 3, sc8 = (tid & 7) << 3;  // staging

  for (int kt = 0; kt < 32; ++kt) {
    __syncthreads();   // prev iter's reads of Ks/Vs done
    {
      int4 kv0 = *(const int4*)(kbase  + (size_t)(kt * 64 + sr) * INNER + sc8);
      int4 kv1 = *(const int4*)(kbase  + (size_t)(kt * 64 + sr + 32) * INNER + sc8);
      int4 vv0 = *(const int4*)(vtbase + (size_t)sr * 2048 + kt * 64 + sc8);
      int4 vv1 = *(const int4*)(vtbase + (size_t)(sr + 32) * 2048 + kt * 64 + sc8);
      *(int4*)&Ks[sr * 72 + sc8]        = kv0;
      *(int4*)&Ks[(sr + 32) * 72 + sc8] = kv1;
      *(int4*)&Vs[sr * 72 + sc8]        = vv0;
      *(int4*)&Vs[(sr + 32) * 72 + sc8] = vv1;
    }
    __syncthreads();

    // S = Q K^T (Q pre-scaled): B-frag = K natural [key][d]
    f32x4 s[4];
#pragma unroll
    for (int j = 0; j < 4; ++j) s[j] = f32x4{0.f, 0.f, 0.f, 0.f};
#pragma unroll
    for (int ks = 0; ks < 2; ++ks) {
#pragma unroll
      for (int j = 0; j < 4; ++j) {
        bf16x8 bk = *(const bf16x8*)&Ks[(j * 16 + l16) * 72 + ks * 32 + quad * 8];
        s[j] = MFMA16(aq[ks], bk, s[j]);
      }
    }

    // online softmax; lane owns rows quad*4+r, cols spread over l16
#pragma unroll
    for (int r = 0; r < 4; ++r) {
      float mx = fmaxf(fmaxf(s[0][r], s[1][r]), fmaxf(s[2][r], s[3][r]));
#pragma unroll
      for (int d = 1; d < 16; d <<= 1) mx = fmaxf(mx, __shfl_xor(mx, d, 64));
      float mnew = fmaxf(m_r[r], mx);
      float alpha = __expf(m_r[r] - mnew);
      float rs = 0.f;
#pragma unroll
      for (int j = 0; j < 4; ++j) {
        float p = __expf(s[j][r] - mnew);
        s[j][r] = p;
        rs += p;
      }
#pragma unroll
      for (int d = 1; d < 16; d <<= 1) rs += __shfl_xor(rs, d, 64);
      l_r[r] = l_r[r] * alpha + rs;
      m_r[r] = mnew;
      o[0][r] *= alpha; o[1][r] *= alpha; o[2][r] *= alpha; o[3][r] *= alpha;
    }

    // P: C-layout -> LDS -> A-layout (per-wave private rows)
#pragma unroll
    for (int j = 0; j < 4; ++j)
#pragma unroll
      for (int r = 0; r < 4; ++r)
        Ps[(w * 16 + quad * 4 + r) * 72 + j * 16 + l16] = (bf16_t)s[j][r];
    __syncthreads();

    // O += P V : B-frag = Vt [d][key]
#pragma unroll
    for (int ks = 0; ks < 2; ++ks) {
      bf16x8 ap = *(const bf16x8*)&Ps[(w * 16 + l16) * 72 + ks * 32 + quad * 8];
#pragma unroll
      for (int dt = 0; dt < 4; ++dt) {
        bf16x8 bv = *(const bf16x8*)&Vs[(dt * 16 + l16) * 72 + ks * 32 + quad * 8];
        o[dt] = MFMA16(ap, bv, o[dt]);
      }
    }
  }

  // epilogue: normalize by l, write attention output [4096][512] bf16
  bf16_t* aout = AO + ((size_t)(b * 2048 + qt * 64 + w * 16 + quad * 4)) * INNER + h * DHEAD;
#pragma unroll
  for (int dt = 0; dt < 4; ++dt)
#pragma unroll
    for (int r = 0; r < 4; ++r)
      aout[(size_t)r * INNER + dt * 16 + l16] = (bf16_t)(o[dt][r] / l_r[r]);
}

// ---------- launch ----------
extern "C" void kernel_launch(void* const* d_in, const int* in_sizes, int n_in,
                              void* d_out, int out_size, void* d_ws, size_t ws_size,
                              hipStream_t stream) {
  const float* x   = (const float*)d_in[0];
  const float* ctx = (const float*)d_in[1];
  const float* Wq  = (const float*)d_in[2];
  const float* Wk  = (const float*)d_in[3];
  const float* Wv  = (const float*)d_in[4];
  const float* Wo  = (const float*)d_in[5];
  const float* bo  = (const float*)d_in[6];
  float* out = (float*)d_out;

  char* ws = (char*)d_ws;
  // workspace layout (bytes)
  bf16_t* xb  = (bf16_t*)(ws + 0);          //  8 MB  [4096][1024]
  bf16_t* cb  = (bf16_t*)(ws + 8388608);    //  8 MB  [4096][1024]
  bf16_t* WqT = (bf16_t*)(ws + 16777216);   //  1 MB  [512][1024]
  bf16_t* WkT = (bf16_t*)(ws + 17825792);   //  1 MB
  bf16_t* WvT = (bf16_t*)(ws + 18874368);   //  1 MB
  bf16_t* WoT = (bf16_t*)(ws + 19922944);   //  1 MB  [1024][512]
  bf16_t* Qb  = (bf16_t*)(ws + 20971520);   //  4 MB  [4096][512] (pre-scaled by 1/8)
  bf16_t* Kb  = (bf16_t*)(ws + 25165824);   //  4 MB
  bf16_t* Vb  = (bf16_t*)(ws + 29360128);   //  4 MB
  bf16_t* Vt  = (bf16_t*)(ws + 33554432);   //  4 MB  [16][64][2048]
  bf16_t* AO  = (bf16_t*)(ws + 37748736);   //  4 MB  [4096][512]
  // total 40 MB

  // 1. convert inputs to bf16
  cvt_k<<<4096, 256, 0, stream>>>(x,   xb, 1048576);
  cvt_k<<<4096, 256, 0, stream>>>(ctx, cb, 1048576);
  // 2. transpose+convert weights
  wtrans_k<<<dim3(128, 4), 256, 0, stream>>>(Wq, Wk, Wv, Wo, WqT, WkT, WvT, WoT);
  // 3. QKV projections (z: 0=Q scaled, 1=K, 2=V)
  gemm_qkv_k<<<dim3(4, 32, 3), 256, 0, stream>>>(xb, cb, WqT, WkT, WvT, Qb, Kb, Vb);
  // 4. transpose V per (b,h)
  vtrans_k<<<dim3(32, 16), 256, 0, stream>>>(Vb, Vt);
  // 5. flash attention
  attn_k<<<dim3(32, 16), 256, 0, stream>>>(Qb, Kb, Vt, AO);
  // 6. output projection + bias (fp32 out)
  gemm_out_k<<<dim3(8, 32), 256, 0, stream>>>(AO, WoT, bo, out);
}